// Round 19
// baseline (92.711 us; speedup 1.0000x reference)
//
#include <hip/hip_runtime.h>
#include <hip/hip_bf16.h>

typedef __attribute__((ext_vector_type(8))) __bf16 bf16x8;
typedef __attribute__((ext_vector_type(4))) float f32x4;

__device__ __forceinline__ unsigned short f2bf(float f) {
  unsigned int u = __builtin_bit_cast(unsigned int, f);
  u += 0x7fffu + ((u >> 16) & 1u);   // RNE
  return (unsigned short)(u >> 16);
}

__device__ __forceinline__ unsigned int cvtpk_bf16(float a, float b) {
  unsigned int r;
  asm("v_cvt_pk_bf16_f32 %0, %1, %2" : "=v"(r) : "v"(a), "v"(b));
  return r;   // low16 = bf16(a), high16 = bf16(b)
}

__device__ __forceinline__ void gll16(const void* g, void* l) {
  __builtin_amdgcn_global_load_lds(
      (const __attribute__((address_space(1))) void*)g,
      (__attribute__((address_space(3))) void*)l, 16, 0, 0);
}

// read a 16B MFMA fragment from an LDS tile with 128B rows, XOR-swizzled
__device__ __forceinline__ bf16x8 lds_frag(const unsigned short* base, int row, int kbyte) {
  int off = row * 128 + (kbyte ^ ((row & 7) << 4));
  return *(const bf16x8*)((const char*)base + off);
}

// ---------------- merged input converts (1 launch) -------------------------
__global__ __launch_bounds__(256) void prep(
    const float* __restrict__ x, unsigned short* __restrict__ xb,
    const float* __restrict__ wa, unsigned short* __restrict__ waT,
    const float* __restrict__ wp, unsigned short* __restrict__ wpT) {
  __shared__ float tile[32][33];
  const int b = blockIdx.x;
  const int t = threadIdx.x;
  if (b < 4096) {
    int i = (b * 256 + t) * 4;
    float4 v = *(const float4*)(x + i);
    ushort4 o;
    o.x = f2bf(v.x); o.y = f2bf(v.y); o.z = f2bf(v.z); o.w = f2bf(v.w);
    *(ushort4*)(xb + i) = o;
    return;
  }
  const float* in;
  unsigned short* out;
  int bid, N;
  if (b < 7168) { in = wa; out = waT; bid = b - 4096; N = 3072; }
  else          { in = wp; out = wpT; bid = b - 7168; N = 1024; }
  const int K = 1024;
  int nb = N >> 5;
  int bx = bid % nb, by = bid / nb;
  int n0 = bx << 5, k0 = by << 5;
  int c = t & 31, r0 = t >> 5;
#pragma unroll
  for (int i = 0; i < 4; ++i) {
    int r = r0 + i * 8;
    tile[r][c] = in[(size_t)(k0 + r) * N + n0 + c];
  }
  __syncthreads();
#pragma unroll
  for (int i = 0; i < 4; ++i) {
    int r = r0 + i * 8;
    out[(size_t)(n0 + r) * K + k0 + c] = f2bf(tile[c][r]);
  }
}

// ---------------- QKV GEMM: 256x192 tile, 8 waves, r7 pipeline -------------
// 16x16 = 256 blocks = exactly 1 block/CU (fixes the 75% fill of 256x256).
// stage(T+1) into the idle buffer BEFORE compute(T); one __syncthreads per
// K-tile. Waves 2M x 4N, wave tile 128x48 (acc[8][3]). LDS 112KB.
// Epilogue: Q/K direct (guard n<2048); V transposed via freed stage LDS
// (guard d>=0) — handles the boundary-crossing tile bn=10 with both paths.
// Q pre-scaled by 0.125*log2(e) so attention works in exp2 domain.
__global__ __launch_bounds__(512, 2) void gemm_qkv256(
    const unsigned short* __restrict__ A, const unsigned short* __restrict__ Bt,
    const float* __restrict__ bias,
    unsigned short* __restrict__ Qg, unsigned short* __restrict__ Kg,
    unsigned short* __restrict__ Vtg, int K) {
  __shared__ __align__(16) unsigned short SMEM[57344];   // 112 KB
  unsigned short* const A0 = SMEM;                       // 256x64 = 16384
  unsigned short* const B0 = SMEM + 16384;               // 192x64 = 12288
  unsigned short* const A1 = SMEM + 28672;
  unsigned short* const B1 = SMEM + 45056;
  const int t = threadIdx.x;
  const int l = t & 63, lr = l & 15, hi = l >> 4;
  const int w = t >> 6;
  const int wr = w >> 2, wc = w & 3;           // 2M x 4N waves
  const int bid = (int)(blockIdx.x & 7) * 32 + (int)(blockIdx.x >> 3);  // XCD swizzle (256%8==0)
  const int bm = bid >> 4, bn = bid & 15;
  const int m0 = bm << 8, n0 = bn * 192;
  const int wbase = (t & ~63) * 8;

  f32x4 acc[8][3] = {};

  auto stage = [&](int kt, unsigned short* Ad, unsigned short* Bd) {
    const unsigned short* Ab = A + (size_t)m0 * K + kt * 64;
    const unsigned short* Bb = Bt + (size_t)n0 * K + kt * 64;
#pragma unroll
    for (int i = 0; i < 4; ++i) {              // A: 256 rows = 2048 chunks
      int ci = i * 512 + t;
      int row = ci >> 3, cpos = ci & 7;
      int c = cpos ^ (row & 7);                // pre-swizzled global source
      gll16(Ab + (size_t)row * K + c * 8, Ad + i * 4096 + wbase);
    }
#pragma unroll
    for (int i = 0; i < 3; ++i) {              // B: 192 rows = 1536 chunks
      int ci = i * 512 + t;
      int row = ci >> 3, cpos = ci & 7;
      int c = cpos ^ (row & 7);
      gll16(Bb + (size_t)row * K + c * 8, Bd + i * 4096 + wbase);
    }
  };

  auto compute = [&](const unsigned short* Ad, const unsigned short* Bd) {
#pragma unroll
    for (int ks = 0; ks < 2; ++ks) {
      bf16x8 af[8], bv[3];
#pragma unroll
      for (int mi = 0; mi < 8; ++mi)
        af[mi] = lds_frag(Ad, wr * 128 + mi * 16 + lr, ks * 64 + hi * 16);
#pragma unroll
      for (int ni = 0; ni < 3; ++ni)
        bv[ni] = lds_frag(Bd, wc * 48 + ni * 16 + lr, ks * 64 + hi * 16);
      __builtin_amdgcn_s_setprio(1);
#pragma unroll
      for (int mi = 0; mi < 8; ++mi)
#pragma unroll
        for (int ni = 0; ni < 3; ++ni)
          acc[mi][ni] = __builtin_amdgcn_mfma_f32_16x16x32_bf16(af[mi], bv[ni], acc[mi][ni], 0, 0, 0);
      __builtin_amdgcn_s_setprio(0);
    }
  };

  const int nt = K >> 6;                       // 16
  stage(0, A0, B0);
  __syncthreads();
  for (int T = 0; T < nt; ++T) {
    if (T + 1 < nt) stage(T + 1, (T & 1) ? A0 : A1, (T & 1) ? B0 : B1);
    compute((T & 1) ? A1 : A0, (T & 1) ? B1 : B0);
    __syncthreads();   // drains next-tile loads (issued before compute: hidden)
  }

  if (n0 < 2048) {
    // ---- Q/K columns: direct stores (guard handles boundary tile) ----
    const float QSCALE = 0.125f * 1.4426950408889634f;   // exp2-domain attention
#pragma unroll
    for (int mi = 0; mi < 8; ++mi)
#pragma unroll
      for (int ni = 0; ni < 3; ++ni)
#pragma unroll
        for (int r = 0; r < 4; ++r) {
          int m = m0 + wr * 128 + mi * 16 + 4 * hi + r;
          int n = n0 + wc * 48 + ni * 16 + lr;
          if (n < 2048) {
            float v = acc[mi][ni][r] + bias[n];
            int b = m >> 10, s = m & 1023;
            int d = n & 1023;
            int h = d >> 6, di = d & 63;
            int bh = (b << 4) + h;
            if (n < 1024) Qg[((size_t)(bh << 10) + s) * 64 + di] = f2bf(v * QSCALE);
            else          Kg[((size_t)(bh << 10) + s) * 64 + di] = f2bf(v);
          }
        }
  }
  if (n0 + 192 > 2048) {
    // ---- V columns: transpose 192x256 via freed LDS, coalesced out ----
    __syncthreads();                           // all K-loop LDS reads done
#pragma unroll
    for (int mi = 0; mi < 8; ++mi)
#pragma unroll
      for (int ni = 0; ni < 3; ++ni) {
        int nl = wc * 48 + ni * 16 + lr;
        int ml = wr * 128 + mi * 16 + 4 * hi;
        ushort4 pk;
        pk.x = f2bf(acc[mi][ni][0] + bias[n0 + nl]);
        pk.y = f2bf(acc[mi][ni][1] + bias[n0 + nl]);
        pk.z = f2bf(acc[mi][ni][2] + bias[n0 + nl]);
        pk.w = f2bf(acc[mi][ni][3] + bias[n0 + nl]);
        *(ushort4*)&SMEM[nl * 256 + (ml ^ ((nl & 7) << 3))] = pk;
      }
    __syncthreads();
    const int b = m0 >> 10;
    const int sbase = m0 & 1023;               // within-batch sequence base
#pragma unroll
    for (int it = 0; it < 12; ++it) {
      int nl = it * 16 + (t >> 5);             // 0..191
      int s0 = (t & 31) * 8;
      int d = n0 + nl - 2048;
      if (d >= 0) {
        bf16x8 v8 = *(const bf16x8*)&SMEM[nl * 256 + (s0 ^ ((nl & 7) << 3))];
        size_t row = ((size_t)((b << 4) + (d >> 6)) << 6) + (d & 63);
        *(bf16x8*)&Vtg[row * 1024 + sbase + s0] = v8;
      }
    }
  }
}

// ---------------- proj GEMM: 128x128, 4 waves, r7 pipeline -----------------
__global__ __launch_bounds__(256, 2) void gemm_proj128(
    const unsigned short* __restrict__ A, const unsigned short* __restrict__ Bt,
    const float* __restrict__ bias, float* __restrict__ outf,
    int M, int N, int K) {
  __shared__ unsigned short A0[128 * 64], B0[128 * 64];
  __shared__ unsigned short A1[128 * 64], B1[128 * 64];
  const int t = threadIdx.x;
  const int w = t >> 6, l = t & 63, lr = l & 15, hi = l >> 4;
  const int wr = w >> 1, wc = w & 1;
  const int nbn = N >> 7;
  const int nwg = (M >> 7) * nbn;
  int bid = (int)blockIdx.x;
  if ((nwg & 7) == 0) bid = (bid % 8) * (nwg / 8) + bid / 8;  // XCD swizzle
  const int bm = bid / nbn, bn = bid % nbn;
  const int m0 = bm << 7, n0 = bn << 7;
  const int wbase = (t & ~63) * 8;

  f32x4 acc[4][4] = {};

  auto stage = [&](int kt, unsigned short* Ad, unsigned short* Bd) {
    const unsigned short* Ab = A + (size_t)m0 * K + kt * 64;
    const unsigned short* Bb = Bt + (size_t)n0 * K + kt * 64;
#pragma unroll
    for (int i = 0; i < 4; ++i) {
      int ci = i * 256 + t;
      int row = ci >> 3, cpos = ci & 7;
      int c = cpos ^ (row & 7);
      gll16(Ab + (size_t)row * K + c * 8, Ad + i * 2048 + wbase);
      gll16(Bb + (size_t)row * K + c * 8, Bd + i * 2048 + wbase);
    }
  };

  auto compute = [&](const unsigned short* Ad, const unsigned short* Bd) {
#pragma unroll
    for (int ks = 0; ks < 2; ++ks) {
      bf16x8 af[4], bv[4];
#pragma unroll
      for (int mi = 0; mi < 4; ++mi)
        af[mi] = lds_frag(Ad, wr * 64 + mi * 16 + lr, ks * 64 + hi * 16);
#pragma unroll
      for (int ni = 0; ni < 4; ++ni)
        bv[ni] = lds_frag(Bd, wc * 64 + ni * 16 + lr, ks * 64 + hi * 16);
      __builtin_amdgcn_s_setprio(1);
#pragma unroll
      for (int mi = 0; mi < 4; ++mi)
#pragma unroll
        for (int ni = 0; ni < 4; ++ni)
          acc[mi][ni] = __builtin_amdgcn_mfma_f32_16x16x32_bf16(af[mi], bv[ni], acc[mi][ni], 0, 0, 0);
      __builtin_amdgcn_s_setprio(0);
    }
  };

  const int nt = K >> 6;
  stage(0, A0, B0);
  __syncthreads();
  for (int T = 0; T < nt; ++T) {
    if (T + 1 < nt) stage(T + 1, (T & 1) ? A0 : A1, (T & 1) ? B0 : B1);
    compute((T & 1) ? A1 : A0, (T & 1) ? B1 : B0);
    __syncthreads();
  }

#pragma unroll
  for (int mi = 0; mi < 4; ++mi)
#pragma unroll
    for (int ni = 0; ni < 4; ++ni)
#pragma unroll
      for (int r = 0; r < 4; ++r) {
        int m = m0 + wr * 64 + mi * 16 + 4 * hi + r;
        int n = n0 + wc * 64 + ni * 16 + lr;
        outf[(size_t)m * N + n] = acc[mi][ni][r] + bias[n];
      }
}

// ---------------- causal flash attention (r17: balanced qt, 3-barrier) -----
__global__ __launch_bounds__(256) void attn_kernel(
    const unsigned short* __restrict__ Qg, const unsigned short* __restrict__ Kg,
    const unsigned short* __restrict__ Vtg, unsigned short* __restrict__ Og) {
  __shared__ unsigned short K0[64 * 64], K1[64 * 64];
  __shared__ unsigned short Vb[64 * 64];
  __shared__ __align__(16) unsigned short Plds[4][16][72];  // [wave][q][key]
  const int bh = blockIdx.x & 63;
  const int idx = blockIdx.x >> 6;
  const int q0c = idx & 3, j = idx >> 2;
  const int qt = (j == 0) ? 2 * q0c
               : (j == 1) ? 15 - 2 * q0c
               : (j == 2) ? 2 * q0c + 1
                          : 14 - 2 * q0c;     // balanced: every stride-4 class sums 30
  const int t = threadIdx.x;
  const int w = t >> 6, l = t & 63, lr = l & 15, hi = l >> 4;
  const unsigned short* Qbh = Qg + (size_t)bh * 65536;
  const unsigned short* Kbh = Kg + (size_t)bh * 65536;
  const unsigned short* Vbh = Vtg + (size_t)bh * 65536;
  const int q0 = qt * 64 + w * 16;
  const int wbase = (t & ~63) * 8;

  bf16x8 qf[2];
#pragma unroll
  for (int ks = 0; ks < 2; ++ks)
    qf[ks] = *(const bf16x8*)(Qbh + (size_t)(q0 + lr) * 64 + ks * 32 + hi * 8);

  f32x4 ocT[4] = {};           // ocT[c][r] = O[q=lr][d = c*16+4*hi+r]
  float mrun = -1e30f, lrun = 0.f;
  const int thr = w * 16 + lr - 4 * hi;   // mask: key>q  <=>  16c+r > thr

  auto stageK = [&](int kt, unsigned short* Kd) {
#pragma unroll
    for (int i = 0; i < 2; ++i) {
      int ci = i * 256 + t;
      int row = ci >> 3, cpos = ci & 7;
      int c = cpos ^ (row & 7);
      gll16(Kbh + (size_t)(kt * 64 + row) * 64 + c * 8, Kd + i * 2048 + wbase);
    }
  };
  auto stageV = [&](int kt) {
#pragma unroll
    for (int i = 0; i < 2; ++i) {
      int ci = i * 256 + t;
      int row = ci >> 3, cpos = ci & 7;
      int c = cpos ^ (row & 7);
      gll16(Vbh + (size_t)row * 1024 + kt * 64 + c * 8, Vb + i * 2048 + wbase);
    }
  };

  stageK(0, K0);
  stageV(0);

  for (int kt = 0; kt <= qt; ++kt) {
    unsigned short* Kc = (kt & 1) ? K1 : K0;
    unsigned short* Kn = (kt & 1) ? K0 : K1;
    const bool pf = (kt < qt);

    asm volatile("s_waitcnt vmcnt(2)" ::: "memory");   // K(kt) landed
    __builtin_amdgcn_s_barrier();

    if (pf) stageK(kt + 1, Kn);   // issue early; hidden under QK+softmax

    // swapped QK^T: sc[c] = D[key = 16c+4hi+r][q = lr]
    f32x4 sc[4] = {};
    __builtin_amdgcn_s_setprio(1);
#pragma unroll
    for (int c = 0; c < 4; ++c)
#pragma unroll
      for (int ks = 0; ks < 2; ++ks) {
        bf16x8 kf = lds_frag(Kc, c * 16 + lr, ks * 64 + hi * 16);
        sc[c] = __builtin_amdgcn_mfma_f32_16x16x32_bf16(kf, qf[ks], sc[c], 0, 0, 0);
      }
    __builtin_amdgcn_s_setprio(0);
    if (kt == qt) {
#pragma unroll
      for (int c = 0; c < 4; ++c)
#pragma unroll
        for (int r = 0; r < 4; ++r)
          if (c * 16 + r > thr) sc[c][r] = -1e30f;
    }

    // row softmax; defer-max: skip rescale pass when max didn't grow (exact)
    float mx = sc[0][0];
#pragma unroll
    for (int c = 0; c < 4; ++c)
#pragma unroll
      for (int r = 0; r < 4; ++r) mx = fmaxf(mx, sc[c][r]);
    mx = fmaxf(mx, __shfl_xor(mx, 16));
    mx = fmaxf(mx, __shfl_xor(mx, 32));
    if (!__all(mx <= mrun)) {
      float mn = fmaxf(mrun, mx);
      float al = exp2f(mrun - mn);
      mrun = mn;
      lrun *= al;
#pragma unroll
      for (int c = 0; c < 4; ++c)
#pragma unroll
        for (int r = 0; r < 4; ++r) ocT[c][r] *= al;
    }
    float p[4][4], s = 0.f;
#pragma unroll
    for (int c = 0; c < 4; ++c)
#pragma unroll
      for (int r = 0; r < 4; ++r) {
        p[c][r] = exp2f(sc[c][r] - mrun);
        s += p[c][r];
      }
    s += __shfl_xor(s, 16);
    s += __shfl_xor(s, 32);
    lrun += s;

    // P -> Plds[w][q=lr][key] (wave-private), packed b64 writes
#pragma unroll
    for (int c = 0; c < 4; ++c) {
      uint2 pk;
      pk.x = cvtpk_bf16(p[c][0], p[c][1]);
      pk.y = cvtpk_bf16(p[c][2], p[c][3]);
      *(uint2*)&Plds[w][lr][c * 16 + 4 * hi] = pk;
    }
    asm volatile("s_waitcnt lgkmcnt(0)" ::: "memory");
    __builtin_amdgcn_sched_barrier(0);

    bf16x8 pb[2];
#pragma unroll
    for (int ks = 0; ks < 2; ++ks)
      pb[ks] = *(const bf16x8*)(&Plds[w][lr][ks * 32 + hi * 8]);

    if (pf) asm volatile("s_waitcnt vmcnt(2)" ::: "memory");  // V(kt) landed
    else    asm volatile("s_waitcnt vmcnt(0)" ::: "memory");
    __builtin_amdgcn_s_barrier();               // all waves' V(kt) visible

    __builtin_amdgcn_s_setprio(1);
#pragma unroll
    for (int c = 0; c < 4; ++c)
#pragma unroll
      for (int ks = 0; ks < 2; ++ks) {
        bf16x8 vf = lds_frag(Vb, c * 16 + lr, ks * 64 + hi * 16);
        ocT[c] = __builtin_amdgcn_mfma_f32_16x16x32_bf16(vf, pb[ks], ocT[c], 0, 0, 0);
      }
    __builtin_amdgcn_s_setprio(0);
    __builtin_amdgcn_s_barrier();                // all waves done reading Vb
    if (pf) stageV(kt + 1);                      // safe to overwrite Vb now
  }

  const int b = bh >> 4, h = bh & 15;
  const float inv = 1.0f / lrun;
  const size_t rowbase = ((size_t)(b * 1024 + q0 + lr)) * 1024 + h * 64;
#pragma unroll
  for (int c = 0; c < 4; ++c) {
    uint2 o2;
    o2.x = cvtpk_bf16(ocT[c][0] * inv, ocT[c][1] * inv);
    o2.y = cvtpk_bf16(ocT[c][2] * inv, ocT[c][3] * inv);
    *(uint2*)&Og[rowbase + c * 16 + 4 * hi] = o2;
  }
}

extern "C" void kernel_launch(void* const* d_in, const int* in_sizes, int n_in,
                              void* d_out, int out_size, void* d_ws, size_t ws_size,
                              hipStream_t stream) {
  const float* x      = (const float*)d_in[0];
  const float* w_attn = (const float*)d_in[1];
  const float* b_attn = (const float*)d_in[2];
  const float* w_proj = (const float*)d_in[3];
  const float* b_proj = (const float*)d_in[4];
  float* out = (float*)d_out;

  unsigned short* ws  = (unsigned short*)d_ws;
  unsigned short* xb  = ws;                       // [4096,1024] bf16 (reused as Og)
  unsigned short* waT = xb + 4096 * 1024;         // [3072,1024] bf16
  unsigned short* wpT = waT + 3072 * 1024;        // [1024,1024] bf16
  unsigned short* Qg  = wpT + 1024 * 1024;        // [64,1024,64]
  unsigned short* Kg  = Qg + 4194304;             // [64,1024,64]
  unsigned short* Vtg = Kg + 4194304;             // [64,64,1024]
  unsigned short* Og  = xb;                       // alias (x consumed by then)

  prep<<<8192, 256, 0, stream>>>(x, xb, w_attn, waT, w_proj, wpT);
  gemm_qkv256<<<256, 512, 0, stream>>>(xb, waT, b_attn, Qg, Kg, Vtg, 1024);
  attn_kernel<<<1024, 256, 0, stream>>>(Qg, Kg, Vtg, Og);
  gemm_proj128<<<32 * 8, 256, 0, stream>>>(Og, wpT, b_proj, (float*)out, 4096, 1024, 1024);
}

// Round 20
// 91.191 us; speedup vs baseline: 1.0167x; 1.0167x over previous
//
#include <hip/hip_runtime.h>
#include <hip/hip_bf16.h>

typedef __attribute__((ext_vector_type(8))) __bf16 bf16x8;
typedef __attribute__((ext_vector_type(4))) float f32x4;

__device__ __forceinline__ unsigned short f2bf(float f) {
  unsigned int u = __builtin_bit_cast(unsigned int, f);
  u += 0x7fffu + ((u >> 16) & 1u);   // RNE
  return (unsigned short)(u >> 16);
}

__device__ __forceinline__ unsigned int cvtpk_bf16(float a, float b) {
  unsigned int r;
  asm("v_cvt_pk_bf16_f32 %0, %1, %2" : "=v"(r) : "v"(a), "v"(b));
  return r;   // low16 = bf16(a), high16 = bf16(b)
}

__device__ __forceinline__ void gll16(const void* g, void* l) {
  __builtin_amdgcn_global_load_lds(
      (const __attribute__((address_space(1))) void*)g,
      (__attribute__((address_space(3))) void*)l, 16, 0, 0);
}

// read a 16B MFMA fragment from an LDS tile with 128B rows, XOR-swizzled
__device__ __forceinline__ bf16x8 lds_frag(const unsigned short* base, int row, int kbyte) {
  int off = row * 128 + (kbyte ^ ((row & 7) << 4));
  return *(const bf16x8*)((const char*)base + off);
}

// ---------------- merged input converts (1 launch) -------------------------
__global__ __launch_bounds__(256) void prep(
    const float* __restrict__ x, unsigned short* __restrict__ xb,
    const float* __restrict__ wa, unsigned short* __restrict__ waT,
    const float* __restrict__ wp, unsigned short* __restrict__ wpT) {
  __shared__ float tile[32][33];
  const int b = blockIdx.x;
  const int t = threadIdx.x;
  if (b < 4096) {
    int i = (b * 256 + t) * 4;
    float4 v = *(const float4*)(x + i);
    ushort4 o;
    o.x = f2bf(v.x); o.y = f2bf(v.y); o.z = f2bf(v.z); o.w = f2bf(v.w);
    *(ushort4*)(xb + i) = o;
    return;
  }
  const float* in;
  unsigned short* out;
  int bid, N;
  if (b < 7168) { in = wa; out = waT; bid = b - 4096; N = 3072; }
  else          { in = wp; out = wpT; bid = b - 7168; N = 1024; }
  const int K = 1024;
  int nb = N >> 5;
  int bx = bid % nb, by = bid / nb;
  int n0 = bx << 5, k0 = by << 5;
  int c = t & 31, r0 = t >> 5;
#pragma unroll
  for (int i = 0; i < 4; ++i) {
    int r = r0 + i * 8;
    tile[r][c] = in[(size_t)(k0 + r) * N + n0 + c];
  }
  __syncthreads();
#pragma unroll
  for (int i = 0; i < 4; ++i) {
    int r = r0 + i * 8;
    out[(size_t)(n0 + r) * K + k0 + c] = f2bf(tile[c][r]);
  }
}

// ---------------- QKV GEMM: 256x256, 8 waves, r7 pipeline ------------------
// stage(T+1) into the idle buffer BEFORE compute(T); one __syncthreads per
// K-tile. Epilogue: Q/K direct; V transposed via the freed 128KB stage LDS.
// Q pre-scaled by 0.125*log2(e) so attention works in exp2 domain.
__global__ __launch_bounds__(512, 2) void gemm_qkv256(
    const unsigned short* __restrict__ A, const unsigned short* __restrict__ Bt,
    const float* __restrict__ bias,
    unsigned short* __restrict__ Qg, unsigned short* __restrict__ Kg,
    unsigned short* __restrict__ Vtg, int K) {
  __shared__ __align__(16) unsigned short SMEM[65536];   // 128 KB
  unsigned short* const A0 = SMEM;
  unsigned short* const B0 = SMEM + 16384;
  unsigned short* const A1 = SMEM + 32768;
  unsigned short* const B1 = SMEM + 49152;
  const int t = threadIdx.x;
  const int l = t & 63, lr = l & 15, hi = l >> 4;
  const int w = t >> 6;
  const int wr = w >> 2, wc = w & 3;           // 2M x 4N waves
  const int bid = (int)(blockIdx.x % 8) * 24 + (int)(blockIdx.x / 8);  // XCD swizzle
  const int bm = bid / 12, bn = bid % 12;
  const int m0 = bm << 8, n0 = bn << 8;
  const int wbase = (t & ~63) * 8;

  f32x4 acc[8][4] = {};

  auto stage = [&](int kt, unsigned short* Ad, unsigned short* Bd) {
    const unsigned short* Ab = A + (size_t)m0 * K + kt * 64;
    const unsigned short* Bb = Bt + (size_t)n0 * K + kt * 64;
#pragma unroll
    for (int i = 0; i < 4; ++i) {
      int ci = i * 512 + t;
      int row = ci >> 3, cpos = ci & 7;
      int c = cpos ^ (row & 7);                // pre-swizzled global source
      gll16(Ab + (size_t)row * K + c * 8, Ad + i * 4096 + wbase);
      gll16(Bb + (size_t)row * K + c * 8, Bd + i * 4096 + wbase);
    }
  };

  auto compute = [&](const unsigned short* Ad, const unsigned short* Bd) {
#pragma unroll
    for (int ks = 0; ks < 2; ++ks) {
      bf16x8 af[8], bv[4];
#pragma unroll
      for (int mi = 0; mi < 8; ++mi)
        af[mi] = lds_frag(Ad, wr * 128 + mi * 16 + lr, ks * 64 + hi * 16);
#pragma unroll
      for (int ni = 0; ni < 4; ++ni)
        bv[ni] = lds_frag(Bd, wc * 64 + ni * 16 + lr, ks * 64 + hi * 16);
      __builtin_amdgcn_s_setprio(1);
#pragma unroll
      for (int mi = 0; mi < 8; ++mi)
#pragma unroll
        for (int ni = 0; ni < 4; ++ni)
          acc[mi][ni] = __builtin_amdgcn_mfma_f32_16x16x32_bf16(af[mi], bv[ni], acc[mi][ni], 0, 0, 0);
      __builtin_amdgcn_s_setprio(0);
    }
  };

  const int nt = K >> 6;                       // 16
  stage(0, A0, B0);
  __syncthreads();
  for (int T = 0; T < nt; ++T) {
    if (T + 1 < nt) stage(T + 1, (T & 1) ? A0 : A1, (T & 1) ? B0 : B1);
    compute((T & 1) ? A1 : A0, (T & 1) ? B1 : B0);
    __syncthreads();   // drains next-tile loads (issued before compute: hidden)
  }

  if (n0 < 2048) {
    // ---- Q/K blocks: direct stores ----
    const float QSCALE = 0.125f * 1.4426950408889634f;   // exp2-domain attention
#pragma unroll
    for (int mi = 0; mi < 8; ++mi)
#pragma unroll
      for (int ni = 0; ni < 4; ++ni)
#pragma unroll
        for (int r = 0; r < 4; ++r) {
          int m = m0 + wr * 128 + mi * 16 + 4 * hi + r;
          int n = n0 + wc * 64 + ni * 16 + lr;
          float v = acc[mi][ni][r] + bias[n];
          int b = m >> 10, s = m & 1023;
          int d = n & 1023;
          int h = d >> 6, di = d & 63;
          int bh = (b << 4) + h;
          if (n < 1024) Qg[((size_t)(bh << 10) + s) * 64 + di] = f2bf(v * QSCALE);
          else          Kg[((size_t)(bh << 10) + s) * 64 + di] = f2bf(v);
        }
  } else {
    // ---- V block: transpose 256x256 tile via freed LDS, coalesced out ----
    __syncthreads();                           // all K-loop LDS reads done
#pragma unroll
    for (int mi = 0; mi < 8; ++mi)
#pragma unroll
      for (int ni = 0; ni < 4; ++ni) {
        int nl = wc * 64 + ni * 16 + lr;
        int ml = wr * 128 + mi * 16 + 4 * hi;
        ushort4 pk;
        pk.x = f2bf(acc[mi][ni][0] + bias[n0 + nl]);
        pk.y = f2bf(acc[mi][ni][1] + bias[n0 + nl]);
        pk.z = f2bf(acc[mi][ni][2] + bias[n0 + nl]);
        pk.w = f2bf(acc[mi][ni][3] + bias[n0 + nl]);
        *(ushort4*)&SMEM[nl * 256 + (ml ^ ((nl & 7) << 3))] = pk;
      }
    __syncthreads();
    const int b = m0 >> 10;
    const int sbase = m0 & 1023;               // within-batch sequence base
#pragma unroll
    for (int it = 0; it < 16; ++it) {
      int nl = it * 16 + (t >> 5);
      int s0 = (t & 31) * 8;
      bf16x8 v8 = *(const bf16x8*)&SMEM[nl * 256 + (s0 ^ ((nl & 7) << 3))];
      int d = n0 - 2048 + nl;
      size_t row = ((size_t)((b << 4) + (d >> 6)) << 6) + (d & 63);
      *(bf16x8*)&Vtg[row * 1024 + sbase + s0] = v8;
    }
  }
}

// ---------------- proj GEMM: 128x128, 4 waves, r7 pipeline -----------------
__global__ __launch_bounds__(256, 2) void gemm_proj128(
    const unsigned short* __restrict__ A, const unsigned short* __restrict__ Bt,
    const float* __restrict__ bias, float* __restrict__ outf,
    int M, int N, int K) {
  __shared__ unsigned short A0[128 * 64], B0[128 * 64];
  __shared__ unsigned short A1[128 * 64], B1[128 * 64];
  const int t = threadIdx.x;
  const int w = t >> 6, l = t & 63, lr = l & 15, hi = l >> 4;
  const int wr = w >> 1, wc = w & 1;
  const int nbn = N >> 7;
  const int nwg = (M >> 7) * nbn;
  int bid = (int)blockIdx.x;
  if ((nwg & 7) == 0) bid = (bid % 8) * (nwg / 8) + bid / 8;  // XCD swizzle
  const int bm = bid / nbn, bn = bid % nbn;
  const int m0 = bm << 7, n0 = bn << 7;
  const int wbase = (t & ~63) * 8;

  f32x4 acc[4][4] = {};

  auto stage = [&](int kt, unsigned short* Ad, unsigned short* Bd) {
    const unsigned short* Ab = A + (size_t)m0 * K + kt * 64;
    const unsigned short* Bb = Bt + (size_t)n0 * K + kt * 64;
#pragma unroll
    for (int i = 0; i < 4; ++i) {
      int ci = i * 256 + t;
      int row = ci >> 3, cpos = ci & 7;
      int c = cpos ^ (row & 7);
      gll16(Ab + (size_t)row * K + c * 8, Ad + i * 2048 + wbase);
      gll16(Bb + (size_t)row * K + c * 8, Bd + i * 2048 + wbase);
    }
  };

  auto compute = [&](const unsigned short* Ad, const unsigned short* Bd) {
#pragma unroll
    for (int ks = 0; ks < 2; ++ks) {
      bf16x8 af[4], bv[4];
#pragma unroll
      for (int mi = 0; mi < 4; ++mi)
        af[mi] = lds_frag(Ad, wr * 64 + mi * 16 + lr, ks * 64 + hi * 16);
#pragma unroll
      for (int ni = 0; ni < 4; ++ni)
        bv[ni] = lds_frag(Bd, wc * 64 + ni * 16 + lr, ks * 64 + hi * 16);
      __builtin_amdgcn_s_setprio(1);
#pragma unroll
      for (int mi = 0; mi < 4; ++mi)
#pragma unroll
        for (int ni = 0; ni < 4; ++ni)
          acc[mi][ni] = __builtin_amdgcn_mfma_f32_16x16x32_bf16(af[mi], bv[ni], acc[mi][ni], 0, 0, 0);
      __builtin_amdgcn_s_setprio(0);
    }
  };

  const int nt = K >> 6;
  stage(0, A0, B0);
  __syncthreads();
  for (int T = 0; T < nt; ++T) {
    if (T + 1 < nt) stage(T + 1, (T & 1) ? A0 : A1, (T & 1) ? B0 : B1);
    compute((T & 1) ? A1 : A0, (T & 1) ? B1 : B0);
    __syncthreads();
  }

#pragma unroll
  for (int mi = 0; mi < 4; ++mi)
#pragma unroll
    for (int ni = 0; ni < 4; ++ni)
#pragma unroll
      for (int r = 0; r < 4; ++r) {
        int m = m0 + wr * 64 + mi * 16 + 4 * hi + r;
        int n = n0 + wc * 64 + ni * 16 + lr;
        outf[(size_t)m * N + n] = acc[mi][ni][r] + bias[n];
      }
}

// ---------------- causal flash attention (r13 structure + qt balance) ------
// qt decoded via a per-class permutation so each CU's 4 resident blocks have
// equal total iterations: classes {idx mod 4} map j=idx>>2 to
// {2q0, 15-2q0, 2q0+1, 14-2q0} — every stride-4 set sums 30 (+4) = 34 iters.
__global__ __launch_bounds__(256) void attn_kernel(
    const unsigned short* __restrict__ Qg, const unsigned short* __restrict__ Kg,
    const unsigned short* __restrict__ Vtg, unsigned short* __restrict__ Og) {
  __shared__ unsigned short K0[64 * 64], K1[64 * 64];
  __shared__ unsigned short Vb[64 * 64];
  __shared__ __align__(16) unsigned short Plds[4][16][72];  // [wave][q][key]
  const int bh = blockIdx.x & 63;
  const int idx = blockIdx.x >> 6;
  const int q0c = idx & 3, j = idx >> 2;
  const int qt = (j == 0) ? 2 * q0c
               : (j == 1) ? 15 - 2 * q0c
               : (j == 2) ? 2 * q0c + 1
                          : 14 - 2 * q0c;
  const int t = threadIdx.x;
  const int w = t >> 6, l = t & 63, lr = l & 15, hi = l >> 4;
  const unsigned short* Qbh = Qg + (size_t)bh * 65536;
  const unsigned short* Kbh = Kg + (size_t)bh * 65536;
  const unsigned short* Vbh = Vtg + (size_t)bh * 65536;
  const int q0 = qt * 64 + w * 16;
  const int wbase = (t & ~63) * 8;

  bf16x8 qf[2];
#pragma unroll
  for (int ks = 0; ks < 2; ++ks)
    qf[ks] = *(const bf16x8*)(Qbh + (size_t)(q0 + lr) * 64 + ks * 32 + hi * 8);

  f32x4 ocT[4] = {};           // ocT[c][r] = O[q=lr][d = c*16+4*hi+r]
  float mrun = -1e30f, lrun = 0.f;
  const int thr = w * 16 + lr - 4 * hi;   // mask: key>q  <=>  16c+r > thr

  auto stageK = [&](int kt, unsigned short* Kd) {
#pragma unroll
    for (int i = 0; i < 2; ++i) {
      int ci = i * 256 + t;
      int row = ci >> 3, cpos = ci & 7;
      int c = cpos ^ (row & 7);
      gll16(Kbh + (size_t)(kt * 64 + row) * 64 + c * 8, Kd + i * 2048 + wbase);
    }
  };
  auto stageV = [&](int kt) {
#pragma unroll
    for (int i = 0; i < 2; ++i) {
      int ci = i * 256 + t;
      int row = ci >> 3, cpos = ci & 7;
      int c = cpos ^ (row & 7);
      gll16(Vbh + (size_t)row * 1024 + kt * 64 + c * 8, Vb + i * 2048 + wbase);
    }
  };

  stageK(0, K0);
  stageV(0);

  for (int kt = 0; kt <= qt; ++kt) {
    unsigned short* Kc = (kt & 1) ? K1 : K0;
    unsigned short* Kn = (kt & 1) ? K0 : K1;
    const bool pf = (kt < qt);

    asm volatile("s_waitcnt vmcnt(2)" ::: "memory");   // K(kt) landed
    __builtin_amdgcn_s_barrier();

    if (pf) stageK(kt + 1, Kn);   // issue early; hidden under QK+softmax

    // swapped QK^T: sc[c] = D[key = 16c+4hi+r][q = lr]
    f32x4 sc[4] = {};
    __builtin_amdgcn_s_setprio(1);
#pragma unroll
    for (int c = 0; c < 4; ++c)
#pragma unroll
      for (int ks = 0; ks < 2; ++ks) {
        bf16x8 kf = lds_frag(Kc, c * 16 + lr, ks * 64 + hi * 16);
        sc[c] = __builtin_amdgcn_mfma_f32_16x16x32_bf16(kf, qf[ks], sc[c], 0, 0, 0);
      }
    __builtin_amdgcn_s_setprio(0);
    if (kt == qt) {
#pragma unroll
      for (int c = 0; c < 4; ++c)
#pragma unroll
        for (int r = 0; r < 4; ++r)
          if (c * 16 + r > thr) sc[c][r] = -1e30f;
    }

    // row softmax; defer-max: skip rescale pass when max didn't grow (exact)
    float mx = sc[0][0];
#pragma unroll
    for (int c = 0; c < 4; ++c)
#pragma unroll
      for (int r = 0; r < 4; ++r) mx = fmaxf(mx, sc[c][r]);
    mx = fmaxf(mx, __shfl_xor(mx, 16));
    mx = fmaxf(mx, __shfl_xor(mx, 32));
    if (!__all(mx <= mrun)) {
      float mn = fmaxf(mrun, mx);
      float al = exp2f(mrun - mn);
      mrun = mn;
      lrun *= al;
#pragma unroll
      for (int c = 0; c < 4; ++c)
#pragma unroll
        for (int r = 0; r < 4; ++r) ocT[c][r] *= al;
    }
    float p[4][4], s = 0.f;
#pragma unroll
    for (int c = 0; c < 4; ++c)
#pragma unroll
      for (int r = 0; r < 4; ++r) {
        p[c][r] = exp2f(sc[c][r] - mrun);
        s += p[c][r];
      }
    s += __shfl_xor(s, 16);
    s += __shfl_xor(s, 32);
    lrun += s;

    // P -> Plds[w][q=lr][key] (wave-private), packed b64 writes
#pragma unroll
    for (int c = 0; c < 4; ++c) {
      uint2 pk;
      pk.x = cvtpk_bf16(p[c][0], p[c][1]);
      pk.y = cvtpk_bf16(p[c][2], p[c][3]);
      *(uint2*)&Plds[w][lr][c * 16 + 4 * hi] = pk;
    }
    asm volatile("s_waitcnt lgkmcnt(0)" ::: "memory");
    __builtin_amdgcn_sched_barrier(0);

    bf16x8 pb[2];
#pragma unroll
    for (int ks = 0; ks < 2; ++ks)
      pb[ks] = *(const bf16x8*)(&Plds[w][lr][ks * 32 + hi * 8]);

    if (pf) asm volatile("s_waitcnt vmcnt(2)" ::: "memory");  // V(kt) landed
    else    asm volatile("s_waitcnt vmcnt(0)" ::: "memory");
    __builtin_amdgcn_s_barrier();               // all waves' V(kt) visible

    __builtin_amdgcn_s_setprio(1);
#pragma unroll
    for (int c = 0; c < 4; ++c)
#pragma unroll
      for (int ks = 0; ks < 2; ++ks) {
        bf16x8 vf = lds_frag(Vb, c * 16 + lr, ks * 64 + hi * 16);
        ocT[c] = __builtin_amdgcn_mfma_f32_16x16x32_bf16(vf, pb[ks], ocT[c], 0, 0, 0);
      }
    __builtin_amdgcn_s_setprio(0);
    __builtin_amdgcn_s_barrier();                // all waves done reading Vb
    if (pf) stageV(kt + 1);                      // safe to overwrite Vb now
  }

  const int b = bh >> 4, h = bh & 15;
  const float inv = 1.0f / lrun;
  const size_t rowbase = ((size_t)(b * 1024 + q0 + lr)) * 1024 + h * 64;
#pragma unroll
  for (int c = 0; c < 4; ++c) {
    uint2 o2;
    o2.x = cvtpk_bf16(ocT[c][0] * inv, ocT[c][1] * inv);
    o2.y = cvtpk_bf16(ocT[c][2] * inv, ocT[c][3] * inv);
    *(uint2*)&Og[rowbase + c * 16 + 4 * hi] = o2;
  }
}

extern "C" void kernel_launch(void* const* d_in, const int* in_sizes, int n_in,
                              void* d_out, int out_size, void* d_ws, size_t ws_size,
                              hipStream_t stream) {
  const float* x      = (const float*)d_in[0];
  const float* w_attn = (const float*)d_in[1];
  const float* b_attn = (const float*)d_in[2];
  const float* w_proj = (const float*)d_in[3];
  const float* b_proj = (const float*)d_in[4];
  float* out = (float*)d_out;

  unsigned short* ws  = (unsigned short*)d_ws;
  unsigned short* xb  = ws;                       // [4096,1024] bf16 (reused as Og)
  unsigned short* waT = xb + 4096 * 1024;         // [3072,1024] bf16
  unsigned short* wpT = waT + 3072 * 1024;        // [1024,1024] bf16
  unsigned short* Qg  = wpT + 1024 * 1024;        // [64,1024,64]
  unsigned short* Kg  = Qg + 4194304;             // [64,1024,64]
  unsigned short* Vtg = Kg + 4194304;             // [64,64,1024]
  unsigned short* Og  = xb;                       // alias (x consumed by then)

  prep<<<8192, 256, 0, stream>>>(x, xb, w_attn, waT, w_proj, wpT);
  gemm_qkv256<<<16 * 12, 512, 0, stream>>>(xb, waT, b_attn, Qg, Kg, Vtg, 1024);
  attn_kernel<<<1024, 256, 0, stream>>>(Qg, Kg, Vtg, Og);
  gemm_proj128<<<32 * 8, 256, 0, stream>>>(Og, wpT, b_proj, (float*)out, 4096, 1024, 1024);
}